// Round 5
// baseline (808.824 us; speedup 1.0000x reference)
//
#include <hip/hip_runtime.h>
#include <hip/hip_bf16.h>

typedef __hip_bfloat16 bf16;
typedef __bf16 bf8v __attribute__((ext_vector_type(8)));
typedef __bf16 bf4v __attribute__((ext_vector_type(4)));
typedef float f4v __attribute__((ext_vector_type(4)));

static __device__ __forceinline__ float tf(const bf16 v) { return __bfloat162float(v); }

// load from an input buffer whose dtype is decided at runtime (f32 flag)
static __device__ __forceinline__ float ldv(const void* p, size_t i, bool f32) {
    return f32 ? ((const float*)p)[i] : tf(((const bf16*)p)[i]);
}

// async global->LDS, 16B per lane; LDS placement = wave-uniform base + lane*16
static __device__ __forceinline__ void gld_lds16(const bf16* g, __bf16* l) {
    __builtin_amdgcn_global_load_lds(
        (const __attribute__((address_space(1))) void*)g,
        (__attribute__((address_space(3))) void*)l, 16, 0, 0);
}

constexpr int Bz = 16, Lz = 1024, DM = 512, DI = 1024, ST = 16, DC = 4, RK = 32, OD = 128;
constexpr int Mrows = Bz * Lz;           // 16384
constexpr int XD = RK + 2 * ST;          // 64 (x_dbl row)
constexpr int NC = 16, CT = Lz / NC;     // scan chunks (16 x 64 steps)
constexpr int FC_KC = 512;               // K-slice per FC block
constexpr int FC_BLOCKS = (Lz * DM) / FC_KC;   // 1024
constexpr float LOG2E = 1.4426950408889634f;

// -------- dtype probe: sample even bf16 halves of x; f32 data -> wild values --------
__global__ void detect_kernel(const void* __restrict__ xp, int* __restrict__ flag) {
    int i = blockIdx.x * 256 + threadIdx.x;          // 0..65535
    const bf16* p = (const bf16*)xp;
    float v = tf(p[(size_t)i * 64]);                 // even idx = low half if f32
    if (!(fabsf(v) < 1e4f)) atomicAdd(flag, 1);      // NaN/inf/huge counts
}

// -------- canonicalize x to bf16 (8 elems = 16B per thread) --------
__global__ __launch_bounds__(256) void canon_kernel(const void* __restrict__ src,
                                                    bf16* __restrict__ dst,
                                                    const int* __restrict__ flag) {
    const bool f = (*flag != 0);
    size_t base = ((size_t)blockIdx.x * 256 + threadIdx.x) * 8;
    if (!f) {
        *(uint4*)((__bf16*)dst + base) = *(const uint4*)((const bf16*)src + base);
    } else {
        f4v a = *(const f4v*)((const float*)src + base);
        f4v b = *(const f4v*)((const float*)src + base + 4);
        bf8v o;
        #pragma unroll
        for (int j = 0; j < 4; ++j) { o[j] = (__bf16)a[j]; o[j + 4] = (__bf16)b[j]; }
        *(bf8v*)((__bf16*)dst + base) = o;
    }
}

// -------- 3 weight transposes fused in one dispatch: Wt[n][k] = W[k][n] --------
__global__ __launch_bounds__(256) void transpose3_kernel(const void* __restrict__ W0,
                                                         const void* __restrict__ W1,
                                                         const void* __restrict__ W2,
                                                         bf16* __restrict__ T0,
                                                         bf16* __restrict__ T1,
                                                         bf16* __restrict__ T2,
                                                         const int* __restrict__ flag) {
    const bool f = (*flag != 0);
    __shared__ float tile[32][33];
    int bid = blockIdx.x;
    const void* W; bf16* Wt; int K, N, n0, k0;
    if (bid < 1024) {        // W_in:  [DM][2*DI], grid 64x16
        W = W0; Wt = T0; K = DM; N = 2 * DI; n0 = (bid & 63) * 32; k0 = (bid >> 6) * 32;
    } else if (bid < 1536) { // W_out: [DI][DM], grid 16x32
        int b = bid - 1024;
        W = W1; Wt = T1; K = DI; N = DM; n0 = (b & 15) * 32; k0 = (b >> 4) * 32;
    } else {                 // W_xproj: [DI][XD], grid 2x32
        int b = bid - 1536;
        W = W2; Wt = T2; K = DI; N = XD; n0 = (b & 1) * 32; k0 = (b >> 1) * 32;
    }
    int c = threadIdx.x & 31, r4 = threadIdx.x >> 5;
    #pragma unroll
    for (int i = 0; i < 4; ++i) {
        int r = r4 + i * 8;
        tile[r][c] = ldv(W, (size_t)(k0 + r) * N + n0 + c, f);
    }
    __syncthreads();
    #pragma unroll
    for (int i = 0; i < 4; ++i) {
        int rr = r4 + i * 8;
        Wt[(size_t)(n0 + rr) * K + k0 + c] = __float2bfloat16(tile[c][rr]);
    }
}

// ============ MFMA bf16 GEMM, B^T layout, double-buffered global_load_lds ============
// MR = row-tile (128 or 64). KS = K-split via blockIdx.z (CF32 path accumulates atomically).
template <int MR, int NT, bool SPLIT, bool CF32, int GXL, int KS>
__global__ __launch_bounds__(256) void gemm_bt(const bf16* __restrict__ A, int lda,
                                               const bf16* __restrict__ Bt, int ldb,
                                               void* __restrict__ C0, void* __restrict__ C1,
                                               int ldc, int K) {
    constexpr int MI = (MR == 64) ? 1 : ((NT == 128) ? 4 : 2);
    constexpr int NI = 4;
    constexpr int GX = 1 << GXL;
    __shared__ __align__(16) __bf16 As[2][MR * 32];
    __shared__ __align__(16) __bf16 Bs[2][NT * 32];
    const int tid = threadIdx.x, lane = tid & 63, w = tid >> 6;
    const int l15 = lane & 15, quad = lane >> 4;
    const int wm = (MR == 64) ? w * 16 : ((NT == 128) ? (w >> 1) * 64 : w * 32);
    const int wn = (MR == 64) ? 0 : ((NT == 128) ? (w & 1) * 64 : 0);

    // XCD swizzle: hw id round-robins XCDs; give each XCD a contiguous logical chunk
    const int nwg = GX * gridDim.y;
    const int bid = blockIdx.y * GX + blockIdx.x;
    const int swz = (bid & 7) * (nwg >> 3) + (bid >> 3);
    const int m0 = (swz >> GXL) * MR, n0 = (swz & (GX - 1)) * NT;

    f4v acc[MI][NI];
    #pragma unroll
    for (int i = 0; i < MI; ++i)
        #pragma unroll
        for (int j = 0; j < NI; ++j)
            #pragma unroll
            for (int r = 0; r < 4; ++r) acc[i][j][r] = 0.f;

    auto stage = [&](int bi, int k0) {
        if constexpr (MR == 128) {
            const int arow = w * 32 + (lane >> 2), ach = lane & 3;
            const bf16* g0 = A + (size_t)(m0 + arow) * lda + k0 + ach * 8;
            gld_lds16(g0, &As[bi][w * 1024 + lane * 8]);
            gld_lds16(g0 + (size_t)16 * lda, &As[bi][w * 1024 + 512 + lane * 8]);
        } else {
            const bf16* g0 = A + (size_t)(m0 + (tid >> 2)) * lda + k0 + (tid & 3) * 8;
            gld_lds16(g0, &As[bi][tid * 8]);
        }
        if constexpr (NT == 128) {
            const int arow = w * 32 + (lane >> 2), ach = lane & 3;
            const bf16* g0 = Bt + (size_t)(n0 + arow) * ldb + k0 + ach * 8;
            gld_lds16(g0, &Bs[bi][w * 1024 + lane * 8]);
            gld_lds16(g0 + (size_t)16 * ldb, &Bs[bi][w * 1024 + 512 + lane * 8]);
        } else {
            const bf16* g0 = Bt + (size_t)(n0 + (tid >> 2)) * ldb + k0 + (tid & 3) * 8;
            gld_lds16(g0, &Bs[bi][tid * 8]);
        }
    };

    const int kslice = K / KS;
    const int kbeg = (KS > 1) ? (int)blockIdx.z * kslice : 0;
    const int kend = kbeg + kslice;

    stage(0, kbeg);
    __syncthreads();                       // tile 0 resident
    int cur = 0;
    for (int k0 = kbeg; k0 < kend; k0 += 32) {
        if (k0 + 32 < kend) stage(cur ^ 1, k0 + 32);   // prefetch under compute
        bf8v a[MI], b[NI];
        #pragma unroll
        for (int mi = 0; mi < MI; ++mi)
            a[mi] = *(const bf8v*)&As[cur][(wm + mi * 16 + l15) * 32 + quad * 8];
        #pragma unroll
        for (int ni = 0; ni < NI; ++ni)
            b[ni] = *(const bf8v*)&Bs[cur][(wn + ni * 16 + l15) * 32 + quad * 8];
        #pragma unroll
        for (int mi = 0; mi < MI; ++mi)
            #pragma unroll
            for (int ni = 0; ni < NI; ++ni)
                acc[mi][ni] = __builtin_amdgcn_mfma_f32_16x16x32_bf16(a[mi], b[ni], acc[mi][ni], 0, 0, 0);
        __syncthreads();
        cur ^= 1;
    }
    #pragma unroll
    for (int mi = 0; mi < MI; ++mi)
        #pragma unroll
        for (int ni = 0; ni < NI; ++ni)
            #pragma unroll
            for (int r = 0; r < 4; ++r) {
                int row = m0 + wm + mi * 16 + quad * 4 + r;
                int col = n0 + wn + ni * 16 + l15;
                float v = acc[mi][ni][r];
                if (SPLIT) {
                    if (col < DI) ((bf16*)C0)[(size_t)row * DI + col] = __float2bfloat16(v);
                    else ((bf16*)C1)[(size_t)row * DI + col - DI] =
                             __float2bfloat16(v / (1.f + __expf(-v)));
                } else if (CF32) {
                    if (KS > 1) atomicAdd(&((float*)C0)[(size_t)row * ldc + col], v);
                    else ((float*)C0)[(size_t)row * ldc + col] = v;
                } else {
                    ((bf16*)C0)[(size_t)row * ldc + col] = __float2bfloat16(v);
                }
            }
}

// ---------------- conv (depthwise, causal, DC=4) + SiLU ----------------
__global__ __launch_bounds__(256) void conv_silu_kernel(const bf16* __restrict__ xin,
                                                        const void* __restrict__ conv_w,
                                                        const void* __restrict__ conv_b,
                                                        bf16* __restrict__ xc,
                                                        const int* __restrict__ flag) {
    const bool f = (*flag != 0);
    int g = blockIdx.x * 256 + threadIdx.x;       // g = b*2^20 + t*2^10 + d
    int d = g & (DI - 1);
    int t = (g >> 10) & (Lz - 1);
    int b = g >> 20;
    const bf16* xin_b = xin + (size_t)b * Lz * DI;
    float acc = ldv(conv_b, d, f);
    #pragma unroll
    for (int j = 0; j < DC; ++j) {
        int tt = t + j - (DC - 1);
        if (tt >= 0) acc += tf(xin_b[(size_t)tt * DI + d]) * ldv(conv_w, d * DC + j, f);
    }
    xc[(size_t)g] = __float2bfloat16(acc / (1.f + __expf(-acc)));
}

// ======== chunked selective scan, dt fused in-register (W_dt[:,d] lives in VGPRs) ========
// pass1 computes dt via the rank-32 dot, stores dt (f16) for pass2, and per-chunk h finals.
__global__ __launch_bounds__(256) void scan_pass1(const float* __restrict__ x_dbl,
                                                  const bf16* __restrict__ xc,
                                                  const void* __restrict__ A_log,
                                                  const void* __restrict__ W_dt,
                                                  const void* __restrict__ b_dt,
                                                  _Float16* __restrict__ dtw,
                                                  float* __restrict__ hbuf,
                                                  float* __restrict__ dtsum,
                                                  const int* __restrict__ flag) {
    const bool f = (*flag != 0);
    const int c = blockIdx.x, b = blockIdx.z;
    const int d = blockIdx.y * 256 + threadIdx.x;
    __shared__ float Row[CT][XD];                 // 64 x 64 f32 = 16 KB
    #pragma unroll
    for (int i = 0; i < 4; ++i) {                 // 4096 f32, 4 float4/thread
        int idx = threadIdx.x + i * 256;
        int r = idx >> 4, q = idx & 15;
        *(f4v*)&Row[r][q * 4] =
            *(const f4v*)(x_dbl + ((size_t)(b * Lz + c * CT + r)) * XD + q * 4);
    }
    float W[RK];
    #pragma unroll
    for (int k = 0; k < RK; ++k) W[k] = ldv(W_dt, (size_t)k * DI + d, f);
    const float bdt = ldv(b_dt, d, f);
    float A2[ST];                                 // -exp(A_log) * log2(e), for exp2
    #pragma unroll
    for (int s = 0; s < ST; ++s) A2[s] = -__expf(ldv(A_log, (size_t)d * ST + s, f)) * LOG2E;
    __syncthreads();
    float h[ST] = {};
    float S = 0.f;
    const bf16* xcp = xc + (size_t)(b * Lz + c * CT) * DI + d;
    _Float16*   dtp = dtw + (size_t)(b * Lz + c * CT) * DI + d;
    for (int t = 0; t < CT; ++t) {
        float acc = bdt;
        #pragma unroll
        for (int k = 0; k < RK; ++k) acc += Row[t][k] * W[k];     // LDS broadcast
        float dtv = (acc > 15.f) ? acc : __logf(1.f + __expf(acc));
        dtp[(size_t)t * DI] = (_Float16)dtv;
        float du  = dtv * tf(xcp[(size_t)t * DI]);
        S += dtv;
        #pragma unroll
        for (int s = 0; s < ST; ++s)
            h[s] = h[s] * exp2f(dtv * A2[s]) + du * Row[t][RK + s];
    }
    float* hp = hbuf + ((size_t)(b * DI + d) * NC + c) * 16;
    #pragma unroll
    for (int s = 0; s < ST; ++s) hp[s] = h[s];
    dtsum[(size_t)(b * DI + d) * NC + c] = S;
}

// prefix over chunks, parallel in (b,d,s): 1024 blocks x 256 thr
__global__ __launch_bounds__(256) void scan_prefix(float* __restrict__ hbuf,
                                                   const float* __restrict__ dtsum,
                                                   const void* __restrict__ A_log,
                                                   const int* __restrict__ flag) {
    const bool f = (*flag != 0);
    int g = blockIdx.x * 256 + threadIdx.x;       // (b*DI + d)*16 + s
    int s = g & 15, g2 = g >> 4;
    int d = g2 & (DI - 1);
    float A2 = -__expf(ldv(A_log, (size_t)d * ST + s, f)) * LOG2E;
    float hrun = 0.f;
    for (int c = 0; c < NC; ++c) {
        size_t idx = ((size_t)g2 * NC + c) * 16 + s;
        float he = hbuf[idx];
        float S = dtsum[(size_t)g2 * NC + c];
        hbuf[idx] = hrun;                          // h_in for chunk c
        hrun = hrun * exp2f(A2 * S) + he;
    }
}

// pass2: reads stored dt (f16); stages only B,C cols; computes y and gates with silu(z)
__global__ __launch_bounds__(256) void scan_pass2(const float* __restrict__ x_dbl,
                                                  const _Float16* __restrict__ dtw,
                                                  const bf16* __restrict__ xc,
                                                  const void* __restrict__ A_log,
                                                  const void* __restrict__ Dp,
                                                  bf16* __restrict__ yzs,   // in: silu(z), out: y
                                                  const float* __restrict__ hbuf,
                                                  const int* __restrict__ flag) {
    const bool f = (*flag != 0);
    const int c = blockIdx.x, b = blockIdx.z;
    const int d = blockIdx.y * 256 + threadIdx.x;
    __shared__ float BC[CT][32];                  // [t][0:16)=B, [16:32)=C ; 8 KB
    #pragma unroll
    for (int i = 0; i < 2; ++i) {                 // 2048 f32, 2 float4/thread
        int idx = threadIdx.x + i * 256;
        int r = idx >> 3, q = idx & 7;
        *(f4v*)&BC[r][q * 4] =
            *(const f4v*)(x_dbl + ((size_t)(b * Lz + c * CT + r)) * XD + RK + q * 4);
    }
    float A2[ST];
    #pragma unroll
    for (int s = 0; s < ST; ++s) A2[s] = -__expf(ldv(A_log, (size_t)d * ST + s, f)) * LOG2E;
    float Dp_d = ldv(Dp, d, f);
    __syncthreads();
    float h[ST];
    const float* hp = hbuf + ((size_t)(b * DI + d) * NC + c) * 16;
    #pragma unroll
    for (int s = 0; s < ST; ++s) h[s] = hp[s];
    const _Float16* dtp = dtw + (size_t)(b * Lz + c * CT) * DI + d;
    const bf16*     xcp = xc + (size_t)(b * Lz + c * CT) * DI + d;
    bf16*           yzp = yzs + (size_t)(b * Lz + c * CT) * DI + d;
    for (int t = 0; t < CT; ++t) {
        float dtv = (float)dtp[(size_t)t * DI];
        float u   = tf(xcp[(size_t)t * DI]);
        float du  = dtv * u;
        float p = 0.f;
        #pragma unroll
        for (int s = 0; s < ST; ++s) {
            h[s] = h[s] * exp2f(dtv * A2[s]) + du * BC[t][s];
            p += h[s] * BC[t][16 + s];
        }
        float zz = tf(yzp[(size_t)t * DI]);
        yzp[(size_t)t * DI] = __float2bfloat16((p + Dp_d * u) * zz);
    }
}

// ---------------- final FC: out[b][n] = sum_k out_pre[b][k] * W_fc[k][n] ----------------
__global__ __launch_bounds__(256) void fc_partial_kernel(const bf16* __restrict__ out_pre,
                                                         const void* __restrict__ W_fc,
                                                         float* __restrict__ part,
                                                         const int* __restrict__ flag) {
    const bool f = (*flag != 0);
    __shared__ __align__(16) float u_lds[FC_KC][16];   // 32 KB, k-major
    const int tid = threadIdx.x;
    const int k0 = blockIdx.x * FC_KC;

    // stage u = out_pre[b][k0..k0+512) -> f32 LDS
    #pragma unroll
    for (int i = 0; i < 4; ++i) {
        int cid = tid + i * 256;                  // 0..1023
        int b = cid & 15, c8 = cid >> 4;          // 16 rows x 64 chunks of 8
        bf8v v = *(const bf8v*)&out_pre[(size_t)b * (Lz * DM) + k0 + c8 * 8];
        #pragma unroll
        for (int j = 0; j < 8; ++j) u_lds[c8 * 8 + j][b] = (float)v[j];
    }
    __syncthreads();

    const int ng = tid & 31, kr = tid >> 5;       // 32 col-groups x 8 k-subrows
    f4v acc[16];
    #pragma unroll
    for (int b = 0; b < 16; ++b)
        #pragma unroll
        for (int c = 0; c < 4; ++c) acc[b][c] = 0.f;

    if (f) {
        const float* Wp = (const float*)W_fc + (size_t)(k0 + kr) * OD + ng * 4;
        #pragma unroll 4
        for (int kk = 0; kk < FC_KC; kk += 8) {
            f4v w4 = *(const f4v*)(Wp + (size_t)kk * OD);
            int kl = kk + kr;
            #pragma unroll
            for (int q = 0; q < 4; ++q) {
                f4v uq = *(const f4v*)&u_lds[kl][q * 4];
                #pragma unroll
                for (int c = 0; c < 4; ++c) acc[q * 4 + c] += uq[c] * w4;
            }
        }
    } else {
        const bf16* Wp = (const bf16*)W_fc + (size_t)(k0 + kr) * OD + ng * 4;
        #pragma unroll 4
        for (int kk = 0; kk < FC_KC; kk += 8) {
            bf4v wv = *(const bf4v*)(Wp + (size_t)kk * OD);
            f4v w4;
            #pragma unroll
            for (int c = 0; c < 4; ++c) w4[c] = (float)wv[c];
            int kl = kk + kr;
            #pragma unroll
            for (int q = 0; q < 4; ++q) {
                f4v uq = *(const f4v*)&u_lds[kl][q * 4];
                #pragma unroll
                for (int c = 0; c < 4; ++c) acc[q * 4 + c] += uq[c] * w4;
            }
        }
    }

    // reduce the 8 kr partials: shfl halves within wave, then LDS across 4 waves
    #pragma unroll
    for (int b = 0; b < 16; ++b)
        #pragma unroll
        for (int c = 0; c < 4; ++c) acc[b][c] += __shfl_down(acc[b][c], 32);
    __syncthreads();                               // u_lds reads done; reuse as reduce buf
    f4v* redv = (f4v*)&u_lds[0][0];                // 2048 f4v = 32 KB
    const int w = tid >> 6, lane = tid & 63;
    if (lane < 32) {
        #pragma unroll
        for (int b = 0; b < 16; ++b) redv[(b * 4 + w) * 32 + lane] = acc[b];
    }
    __syncthreads();
    #pragma unroll
    for (int i = 0; i < 2; ++i) {
        int og = tid + i * 256;                    // 0..511 = (b, ng)
        int b = og >> 5, ngo = og & 31;
        f4v s = {0.f, 0.f, 0.f, 0.f};
        #pragma unroll
        for (int w2 = 0; w2 < 4; ++w2) s += redv[(b * 4 + w2) * 32 + ngo];
        *(f4v*)&part[(size_t)blockIdx.x * (Bz * OD) + b * OD + ngo * 4] = s;
    }
}

__global__ __launch_bounds__(256) void fc_reduce_kernel(const float* __restrict__ part,
                                                        float* __restrict__ accb) {
    const int o = blockIdx.x * 256 + threadIdx.x;  // 0..2047
    const int s0 = blockIdx.y * (FC_BLOCKS / 16);  // 16 slices of 64 blocks
    float s = 0.f;
    for (int p = s0; p < s0 + FC_BLOCKS / 16; ++p) s += part[(size_t)p * (Bz * OD) + o];
    atomicAdd(&accb[o], s);
}

__global__ void fc_final_kernel(const float* __restrict__ accbuf,
                                const void* __restrict__ b_fc, void* __restrict__ out,
                                const int* __restrict__ flag) {
    const bool f = (*flag != 0);
    int i = blockIdx.x * 256 + threadIdx.x;
    if (i < Bz * OD) {
        float v = accbuf[i] + ldv(b_fc, i & (OD - 1), f);
        if (f) ((float*)out)[i] = v;
        else   ((bf16*)out)[i]  = __float2bfloat16(v);
    }
}

extern "C" void kernel_launch(void* const* d_in, const int* in_sizes, int n_in,
                              void* d_out, int out_size, void* d_ws, size_t ws_size,
                              hipStream_t stream) {
    const void* x       = d_in[0];
    const void* W_in    = d_in[1];
    const void* conv_w  = d_in[2];
    const void* conv_b  = d_in[3];
    const void* W_xproj = d_in[4];
    const void* W_dt    = d_in[5];
    const void* b_dt    = d_in[6];
    const void* A_log   = d_in[7];
    const void* Dp      = d_in[8];
    const void* W_out   = d_in[9];
    const void* W_fc    = d_in[10];
    const void* b_fc    = d_in[11];

    // workspace layout (bytes)
    char* ws = (char*)d_ws;
    bf16*     xin    = (bf16*)(ws);                      // [0,32M); dt(f16) aliases after conv
    _Float16* dtw    = (_Float16*)(ws);                  // 32 MB (xin dead after conv)
    float*    part   = (float*)(ws);                     // 8 MB (dt dead by K7)
    bf16*     yzs    = (bf16*)(ws + 33554432ull);        // [32M,64M) silu(z) -> y
    bf16*     xc     = (bf16*)(ws + 67108864ull);        // [64M,96M)
    float*    x_dbl  = (float*)(ws + 100663296ull);      // [96M,100M) fp32
    bf16*     xb     = (bf16*)(ws + 104857600ull);       // [100M,116M) canonical x; outp aliases
    bf16*     outp   = (bf16*)(ws + 104857600ull);
    float*    hbuf   = (float*)(ws + 167772160ull);      // 160M, 16 MB
    float*    dtsum  = (float*)(ws + 188743680ull);      // 180M, 1 MB
    bf16*     Wt_in  = (bf16*)(ws + 199229440ull);       // 190M, 2 MB  [2048][512]
    bf16*     Wt_out = (bf16*)(ws + 202375168ull);       // 193M, 1 MB  [512][1024]
    bf16*     Wt_xp  = (bf16*)(ws + 204472320ull);       // 195M, 128KB [64][1024]
    float*    accb   = (float*)(ws + 205520896ull);      // 196M, 8 KB
    int*      flag   = (int*)(ws + 206569472ull);        // 197M

    dim3 blk(256);
    hipMemsetAsync(flag, 0, 4, stream);
    detect_kernel<<<256, blk, 0, stream>>>(x, flag);
    // canonicalize / transpose to bf16 B^T (transposes fused into one dispatch)
    canon_kernel<<<(Mrows * DM) / 2048, blk, 0, stream>>>(x, xb, flag);
    transpose3_kernel<<<1600, blk, 0, stream>>>(W_in, W_out, W_xproj,
                                                Wt_in, Wt_out, Wt_xp, flag);
    // K1: [xin | silu(z)] = x @ W_in  (single fused GEMM, split epilogue)
    hipLaunchKernelGGL((gemm_bt<128, 128, true, false, 4, 1>),
                       dim3(2 * DI / 128, Mrows / 128), blk, 0, stream,
                       xb, DM, Wt_in, DM, xin, yzs, DI, DM);
    // K2: xc = silu(conv(xin))
    conv_silu_kernel<<<(Mrows * DI) / 256, blk, 0, stream>>>(xin, conv_w, conv_b, xc, flag);
    // K3: x_dbl = xc @ W_xproj (fp32, 64-row tiles, K-split 2, atomic accumulate)
    hipMemsetAsync(x_dbl, 0, (size_t)Mrows * XD * sizeof(float), stream);
    hipLaunchKernelGGL((gemm_bt<64, 64, false, true, 0, 2>),
                       dim3(1, Mrows / 64, 2), blk, 0, stream,
                       xc, DI, Wt_xp, DI, x_dbl, (void*)0, XD, DI);
    // K5: chunked scan; dt computed once in pass1, stored f16, reused in pass2
    scan_pass1<<<dim3(NC, DI / 256, Bz), blk, 0, stream>>>(x_dbl, xc, A_log, W_dt, b_dt,
                                                           dtw, hbuf, dtsum, flag);
    scan_prefix<<<(Bz * DI * ST) / 256, blk, 0, stream>>>(hbuf, dtsum, A_log, flag);
    scan_pass2<<<dim3(NC, DI / 256, Bz), blk, 0, stream>>>(x_dbl, dtw, xc, A_log,
                                                           Dp, yzs, hbuf, flag);
    // K6: outp = y @ W_out
    hipLaunchKernelGGL((gemm_bt<128, 128, false, false, 2, 1>),
                       dim3(DM / 128, Mrows / 128), blk, 0, stream,
                       yzs, DI, Wt_out, DI, outp, (void*)0, DM, DI);
    // K7: final FC (vectorized, LDS-staged, deterministic partials)
    hipMemsetAsync(accb, 0, Bz * OD * sizeof(float), stream);
    fc_partial_kernel<<<FC_BLOCKS, blk, 0, stream>>>(outp, W_fc, part, flag);
    fc_reduce_kernel<<<dim3((Bz * OD) / 256, 16), blk, 0, stream>>>(part, accb);
    fc_final_kernel<<<(Bz * OD + 255) / 256, blk, 0, stream>>>(accb, b_fc, d_out, flag);
}

// Round 6
// 739.508 us; speedup vs baseline: 1.0937x; 1.0937x over previous
//
#include <hip/hip_runtime.h>
#include <hip/hip_bf16.h>

typedef __hip_bfloat16 bf16;
typedef __bf16 bf8v __attribute__((ext_vector_type(8)));
typedef __bf16 bf4v __attribute__((ext_vector_type(4)));
typedef float f4v __attribute__((ext_vector_type(4)));

static __device__ __forceinline__ float tf(const bf16 v) { return __bfloat162float(v); }

// load from an input buffer whose dtype is decided at runtime (f32 flag)
static __device__ __forceinline__ float ldv(const void* p, size_t i, bool f32) {
    return f32 ? ((const float*)p)[i] : tf(((const bf16*)p)[i]);
}

// async global->LDS, 16B per lane; LDS placement = wave-uniform base + lane*16
static __device__ __forceinline__ void gld_lds16(const bf16* g, __bf16* l) {
    __builtin_amdgcn_global_load_lds(
        (const __attribute__((address_space(1))) void*)g,
        (__attribute__((address_space(3))) void*)l, 16, 0, 0);
}

constexpr int Bz = 16, Lz = 1024, DM = 512, DI = 1024, ST = 16, DC = 4, RK = 32, OD = 128;
constexpr int Mrows = Bz * Lz;           // 16384
constexpr int XD = RK + 2 * ST;          // 64 (x_dbl row)
constexpr int NC = 16, CT = Lz / NC;     // scan chunks (16 x 64 steps)
constexpr int FC_KC = 512;               // K-slice per FC block
constexpr int FC_BLOCKS = (Lz * DM) / FC_KC;   // 1024

// -------- dtype probe: sample even bf16 halves of x; f32 data -> wild values --------
__global__ void detect_kernel(const void* __restrict__ xp, int* __restrict__ flag) {
    int i = blockIdx.x * 256 + threadIdx.x;          // 0..65535
    const bf16* p = (const bf16*)xp;
    float v = tf(p[(size_t)i * 64]);                 // even idx = low half if f32
    if (!(fabsf(v) < 1e4f)) atomicAdd(flag, 1);      // NaN/inf/huge counts
}

// -------- canonicalize x to bf16 (8 elems = 16B per thread) --------
__global__ __launch_bounds__(256) void canon_kernel(const void* __restrict__ src,
                                                    bf16* __restrict__ dst,
                                                    const int* __restrict__ flag) {
    const bool f = (*flag != 0);
    size_t base = ((size_t)blockIdx.x * 256 + threadIdx.x) * 8;
    if (!f) {
        *(uint4*)((__bf16*)dst + base) = *(const uint4*)((const bf16*)src + base);
    } else {
        f4v a = *(const f4v*)((const float*)src + base);
        f4v b = *(const f4v*)((const float*)src + base + 4);
        bf8v o;
        #pragma unroll
        for (int j = 0; j < 4; ++j) { o[j] = (__bf16)a[j]; o[j + 4] = (__bf16)b[j]; }
        *(bf8v*)((__bf16*)dst + base) = o;
    }
}

// -------- 3 weight transposes fused in one dispatch: Wt[n][k] = W[k][n] --------
__global__ __launch_bounds__(256) void transpose3_kernel(const void* __restrict__ W0,
                                                         const void* __restrict__ W1,
                                                         const void* __restrict__ W2,
                                                         bf16* __restrict__ T0,
                                                         bf16* __restrict__ T1,
                                                         bf16* __restrict__ T2,
                                                         const int* __restrict__ flag) {
    const bool f = (*flag != 0);
    __shared__ float tile[32][33];
    int bid = blockIdx.x;
    const void* W; bf16* Wt; int K, N, n0, k0;
    if (bid < 1024) {        // W_in:  [DM][2*DI], grid 64x16
        W = W0; Wt = T0; K = DM; N = 2 * DI; n0 = (bid & 63) * 32; k0 = (bid >> 6) * 32;
    } else if (bid < 1536) { // W_out: [DI][DM], grid 16x32
        int b = bid - 1024;
        W = W1; Wt = T1; K = DI; N = DM; n0 = (b & 15) * 32; k0 = (b >> 4) * 32;
    } else {                 // W_xproj: [DI][XD], grid 2x32
        int b = bid - 1536;
        W = W2; Wt = T2; K = DI; N = XD; n0 = (b & 1) * 32; k0 = (b >> 1) * 32;
    }
    int c = threadIdx.x & 31, r4 = threadIdx.x >> 5;
    #pragma unroll
    for (int i = 0; i < 4; ++i) {
        int r = r4 + i * 8;
        tile[r][c] = ldv(W, (size_t)(k0 + r) * N + n0 + c, f);
    }
    __syncthreads();
    #pragma unroll
    for (int i = 0; i < 4; ++i) {
        int rr = r4 + i * 8;
        Wt[(size_t)(n0 + rr) * K + k0 + c] = __float2bfloat16(tile[c][rr]);
    }
}

// ============ MFMA bf16 GEMM, B^T layout, double-buffered global_load_lds ============
// MR = row-tile (128 or 64). KS = K-split via blockIdx.z (CF32 path accumulates atomically).
template <int MR, int NT, bool SPLIT, bool CF32, int GXL, int KS>
__global__ __launch_bounds__(256) void gemm_bt(const bf16* __restrict__ A, int lda,
                                               const bf16* __restrict__ Bt, int ldb,
                                               void* __restrict__ C0, void* __restrict__ C1,
                                               int ldc, int K) {
    constexpr int MI = (MR == 64) ? 1 : ((NT == 128) ? 4 : 2);
    constexpr int NI = 4;
    constexpr int GX = 1 << GXL;
    __shared__ __align__(16) __bf16 As[2][MR * 32];
    __shared__ __align__(16) __bf16 Bs[2][NT * 32];
    const int tid = threadIdx.x, lane = tid & 63, w = tid >> 6;
    const int l15 = lane & 15, quad = lane >> 4;
    const int wm = (MR == 64) ? w * 16 : ((NT == 128) ? (w >> 1) * 64 : w * 32);
    const int wn = (MR == 64) ? 0 : ((NT == 128) ? (w & 1) * 64 : 0);

    // XCD swizzle: hw id round-robins XCDs; give each XCD a contiguous logical chunk
    const int nwg = GX * gridDim.y;
    const int bid = blockIdx.y * GX + blockIdx.x;
    const int swz = (bid & 7) * (nwg >> 3) + (bid >> 3);
    const int m0 = (swz >> GXL) * MR, n0 = (swz & (GX - 1)) * NT;

    f4v acc[MI][NI];
    #pragma unroll
    for (int i = 0; i < MI; ++i)
        #pragma unroll
        for (int j = 0; j < NI; ++j)
            #pragma unroll
            for (int r = 0; r < 4; ++r) acc[i][j][r] = 0.f;

    auto stage = [&](int bi, int k0) {
        if constexpr (MR == 128) {
            const int arow = w * 32 + (lane >> 2), ach = lane & 3;
            const bf16* g0 = A + (size_t)(m0 + arow) * lda + k0 + ach * 8;
            gld_lds16(g0, &As[bi][w * 1024 + lane * 8]);
            gld_lds16(g0 + (size_t)16 * lda, &As[bi][w * 1024 + 512 + lane * 8]);
        } else {
            const bf16* g0 = A + (size_t)(m0 + (tid >> 2)) * lda + k0 + (tid & 3) * 8;
            gld_lds16(g0, &As[bi][tid * 8]);
        }
        if constexpr (NT == 128) {
            const int arow = w * 32 + (lane >> 2), ach = lane & 3;
            const bf16* g0 = Bt + (size_t)(n0 + arow) * ldb + k0 + ach * 8;
            gld_lds16(g0, &Bs[bi][w * 1024 + lane * 8]);
            gld_lds16(g0 + (size_t)16 * ldb, &Bs[bi][w * 1024 + 512 + lane * 8]);
        } else {
            const bf16* g0 = Bt + (size_t)(n0 + (tid >> 2)) * ldb + k0 + (tid & 3) * 8;
            gld_lds16(g0, &Bs[bi][tid * 8]);
        }
    };

    const int kslice = K / KS;
    const int kbeg = (KS > 1) ? (int)blockIdx.z * kslice : 0;
    const int kend = kbeg + kslice;

    stage(0, kbeg);
    __syncthreads();                       // tile 0 resident
    int cur = 0;
    for (int k0 = kbeg; k0 < kend; k0 += 32) {
        if (k0 + 32 < kend) stage(cur ^ 1, k0 + 32);   // prefetch under compute
        bf8v a[MI], b[NI];
        #pragma unroll
        for (int mi = 0; mi < MI; ++mi)
            a[mi] = *(const bf8v*)&As[cur][(wm + mi * 16 + l15) * 32 + quad * 8];
        #pragma unroll
        for (int ni = 0; ni < NI; ++ni)
            b[ni] = *(const bf8v*)&Bs[cur][(wn + ni * 16 + l15) * 32 + quad * 8];
        #pragma unroll
        for (int mi = 0; mi < MI; ++mi)
            #pragma unroll
            for (int ni = 0; ni < NI; ++ni)
                acc[mi][ni] = __builtin_amdgcn_mfma_f32_16x16x32_bf16(a[mi], b[ni], acc[mi][ni], 0, 0, 0);
        __syncthreads();
        cur ^= 1;
    }
    #pragma unroll
    for (int mi = 0; mi < MI; ++mi)
        #pragma unroll
        for (int ni = 0; ni < NI; ++ni)
            #pragma unroll
            for (int r = 0; r < 4; ++r) {
                int row = m0 + wm + mi * 16 + quad * 4 + r;
                int col = n0 + wn + ni * 16 + l15;
                float v = acc[mi][ni][r];
                if (SPLIT) {
                    if (col < DI) ((bf16*)C0)[(size_t)row * DI + col] = __float2bfloat16(v);
                    else ((bf16*)C1)[(size_t)row * DI + col - DI] =
                             __float2bfloat16(v / (1.f + __expf(-v)));
                } else if (CF32) {
                    if (KS > 1) atomicAdd(&((float*)C0)[(size_t)row * ldc + col], v);
                    else ((float*)C0)[(size_t)row * ldc + col] = v;
                } else {
                    ((bf16*)C0)[(size_t)row * ldc + col] = __float2bfloat16(v);
                }
            }
}

// ---------------- conv (depthwise, causal, DC=4) + SiLU ----------------
__global__ __launch_bounds__(256) void conv_silu_kernel(const bf16* __restrict__ xin,
                                                        const void* __restrict__ conv_w,
                                                        const void* __restrict__ conv_b,
                                                        bf16* __restrict__ xc,
                                                        const int* __restrict__ flag) {
    const bool f = (*flag != 0);
    int g = blockIdx.x * 256 + threadIdx.x;       // g = b*2^20 + t*2^10 + d
    int d = g & (DI - 1);
    int t = (g >> 10) & (Lz - 1);
    int b = g >> 20;
    const bf16* xin_b = xin + (size_t)b * Lz * DI;
    float acc = ldv(conv_b, d, f);
    #pragma unroll
    for (int j = 0; j < DC; ++j) {
        int tt = t + j - (DC - 1);
        if (tt >= 0) acc += tf(xin_b[(size_t)tt * DI + d]) * ldv(conv_w, d * DC + j, f);
    }
    xc[(size_t)g] = __float2bfloat16(acc / (1.f + __expf(-acc)));
}

// ======== chunked selective scan, dt fused in-register (W_dt[:,d] lives in VGPRs) ========
// A structure exploit: reference A[d][s] = -(s+1) for all d, so exp(dtv*A[s]) = E^(s+1)
// with E = exp(dtv*A[0]) -> 1 transcendental + 15 muls instead of 16 transcendentals.
// Verified per-thread at runtime; exact fallback path otherwise.
__global__ __launch_bounds__(256) void scan_pass1(const float* __restrict__ x_dbl,
                                                  const bf16* __restrict__ xc,
                                                  const void* __restrict__ A_log,
                                                  const void* __restrict__ W_dt,
                                                  const void* __restrict__ b_dt,
                                                  float* __restrict__ hbuf,
                                                  float* __restrict__ dtsum,
                                                  const int* __restrict__ flag) {
    const bool f = (*flag != 0);
    const int c = blockIdx.x, b = blockIdx.z;
    const int d = blockIdx.y * 256 + threadIdx.x;
    __shared__ float Row[CT][XD];                 // 64 x 64 f32 = 16 KB
    #pragma unroll
    for (int i = 0; i < 4; ++i) {                 // 4096 f32, 4 float4/thread
        int idx = threadIdx.x + i * 256;
        int r = idx >> 4, q = idx & 15;
        *(f4v*)&Row[r][q * 4] =
            *(const f4v*)(x_dbl + ((size_t)(b * Lz + c * CT + r)) * XD + q * 4);
    }
    float W[RK];
    #pragma unroll
    for (int k = 0; k < RK; ++k) W[k] = ldv(W_dt, (size_t)k * DI + d, f);
    const float bdt = ldv(b_dt, d, f);
    float A[ST];
    #pragma unroll
    for (int s = 0; s < ST; ++s) A[s] = -__expf(ldv(A_log, (size_t)d * ST + s, f));
    bool fast = true;
    #pragma unroll
    for (int s = 0; s < ST; ++s)
        fast = fast && (fabsf(A[s] - (float)(s + 1) * A[0]) <= 1e-4f * (float)(s + 1));
    __syncthreads();
    float h[ST] = {};
    float S = 0.f;
    const bf16* xcp = xc + (size_t)(b * Lz + c * CT) * DI + d;
    if (fast) {
        for (int t = 0; t < CT; ++t) {
            float acc = bdt;
            #pragma unroll
            for (int k = 0; k < RK; ++k) acc += Row[t][k] * W[k];
            float dtv = (acc > 15.f) ? acc : __logf(1.f + __expf(acc));
            float du  = dtv * tf(xcp[(size_t)t * DI]);
            S += dtv;
            float E = __expf(dtv * A[0]);
            float P = 1.f;
            #pragma unroll
            for (int s = 0; s < ST; ++s) {
                P *= E;                            // P = E^(s+1)
                h[s] = h[s] * P + du * Row[t][RK + s];
            }
        }
    } else {
        for (int t = 0; t < CT; ++t) {
            float acc = bdt;
            #pragma unroll
            for (int k = 0; k < RK; ++k) acc += Row[t][k] * W[k];
            float dtv = (acc > 15.f) ? acc : __logf(1.f + __expf(acc));
            float du  = dtv * tf(xcp[(size_t)t * DI]);
            S += dtv;
            #pragma unroll
            for (int s = 0; s < ST; ++s)
                h[s] = h[s] * __expf(dtv * A[s]) + du * Row[t][RK + s];
        }
    }
    float* hp = hbuf + ((size_t)(b * DI + d) * NC + c) * 16;
    #pragma unroll
    for (int s = 0; s < ST; ++s) hp[s] = h[s];
    dtsum[(size_t)(b * DI + d) * NC + c] = S;
}

// prefix over chunks, parallel in (b,d,s): 1024 blocks x 256 thr
__global__ __launch_bounds__(256) void scan_prefix(float* __restrict__ hbuf,
                                                   const float* __restrict__ dtsum,
                                                   const void* __restrict__ A_log,
                                                   const int* __restrict__ flag) {
    const bool f = (*flag != 0);
    int g = blockIdx.x * 256 + threadIdx.x;       // (b*DI + d)*16 + s
    int s = g & 15, g2 = g >> 4;
    int d = g2 & (DI - 1);
    float A1 = -__expf(ldv(A_log, (size_t)d * ST + s, f));
    float hrun = 0.f;
    for (int c = 0; c < NC; ++c) {
        size_t idx = ((size_t)g2 * NC + c) * 16 + s;
        float he = hbuf[idx];
        float S = dtsum[(size_t)g2 * NC + c];
        hbuf[idx] = hrun;                          // h_in for chunk c
        hrun = hrun * __expf(A1 * S) + he;
    }
}

// pass2: recomputes dt (rank-32 dot), full Row stage; computes y, gates with silu(z)
__global__ __launch_bounds__(256) void scan_pass2(const float* __restrict__ x_dbl,
                                                  const bf16* __restrict__ xc,
                                                  const void* __restrict__ A_log,
                                                  const void* __restrict__ W_dt,
                                                  const void* __restrict__ b_dt,
                                                  const void* __restrict__ Dp,
                                                  bf16* __restrict__ yzs,   // in: silu(z), out: y
                                                  const float* __restrict__ hbuf,
                                                  const int* __restrict__ flag) {
    const bool f = (*flag != 0);
    const int c = blockIdx.x, b = blockIdx.z;
    const int d = blockIdx.y * 256 + threadIdx.x;
    __shared__ float Row[CT][XD];                 // 64 x 64 f32 = 16 KB
    #pragma unroll
    for (int i = 0; i < 4; ++i) {
        int idx = threadIdx.x + i * 256;
        int r = idx >> 4, q = idx & 15;
        *(f4v*)&Row[r][q * 4] =
            *(const f4v*)(x_dbl + ((size_t)(b * Lz + c * CT + r)) * XD + q * 4);
    }
    float W[RK];
    #pragma unroll
    for (int k = 0; k < RK; ++k) W[k] = ldv(W_dt, (size_t)k * DI + d, f);
    const float bdt = ldv(b_dt, d, f);
    float A[ST];
    #pragma unroll
    for (int s = 0; s < ST; ++s) A[s] = -__expf(ldv(A_log, (size_t)d * ST + s, f));
    bool fast = true;
    #pragma unroll
    for (int s = 0; s < ST; ++s)
        fast = fast && (fabsf(A[s] - (float)(s + 1) * A[0]) <= 1e-4f * (float)(s + 1));
    float Dp_d = ldv(Dp, d, f);
    __syncthreads();
    float h[ST];
    const float* hp = hbuf + ((size_t)(b * DI + d) * NC + c) * 16;
    #pragma unroll
    for (int s = 0; s < ST; ++s) h[s] = hp[s];
    const bf16* xcp = xc + (size_t)(b * Lz + c * CT) * DI + d;
    bf16*       yzp = yzs + (size_t)(b * Lz + c * CT) * DI + d;
    if (fast) {
        for (int t = 0; t < CT; ++t) {
            float acc = bdt;
            #pragma unroll
            for (int k = 0; k < RK; ++k) acc += Row[t][k] * W[k];
            float dtv = (acc > 15.f) ? acc : __logf(1.f + __expf(acc));
            float u   = tf(xcp[(size_t)t * DI]);
            float du  = dtv * u;
            float E = __expf(dtv * A[0]);
            float P = 1.f;
            float p = 0.f;
            #pragma unroll
            for (int s = 0; s < ST; ++s) {
                P *= E;
                h[s] = h[s] * P + du * Row[t][RK + s];
                p += h[s] * Row[t][RK + ST + s];
            }
            float zz = tf(yzp[(size_t)t * DI]);
            yzp[(size_t)t * DI] = __float2bfloat16((p + Dp_d * u) * zz);
        }
    } else {
        for (int t = 0; t < CT; ++t) {
            float acc = bdt;
            #pragma unroll
            for (int k = 0; k < RK; ++k) acc += Row[t][k] * W[k];
            float dtv = (acc > 15.f) ? acc : __logf(1.f + __expf(acc));
            float u   = tf(xcp[(size_t)t * DI]);
            float du  = dtv * u;
            float p = 0.f;
            #pragma unroll
            for (int s = 0; s < ST; ++s) {
                h[s] = h[s] * __expf(dtv * A[s]) + du * Row[t][RK + s];
                p += h[s] * Row[t][RK + ST + s];
            }
            float zz = tf(yzp[(size_t)t * DI]);
            yzp[(size_t)t * DI] = __float2bfloat16((p + Dp_d * u) * zz);
        }
    }
}

// ---------------- final FC: out[b][n] = sum_k out_pre[b][k] * W_fc[k][n] ----------------
__global__ __launch_bounds__(256) void fc_partial_kernel(const bf16* __restrict__ out_pre,
                                                         const void* __restrict__ W_fc,
                                                         float* __restrict__ part,
                                                         const int* __restrict__ flag) {
    const bool f = (*flag != 0);
    __shared__ __align__(16) float u_lds[FC_KC][16];   // 32 KB, k-major
    const int tid = threadIdx.x;
    const int k0 = blockIdx.x * FC_KC;

    // stage u = out_pre[b][k0..k0+512) -> f32 LDS
    #pragma unroll
    for (int i = 0; i < 4; ++i) {
        int cid = tid + i * 256;                  // 0..1023
        int b = cid & 15, c8 = cid >> 4;          // 16 rows x 64 chunks of 8
        bf8v v = *(const bf8v*)&out_pre[(size_t)b * (Lz * DM) + k0 + c8 * 8];
        #pragma unroll
        for (int j = 0; j < 8; ++j) u_lds[c8 * 8 + j][b] = (float)v[j];
    }
    __syncthreads();

    const int ng = tid & 31, kr = tid >> 5;       // 32 col-groups x 8 k-subrows
    f4v acc[16];
    #pragma unroll
    for (int b = 0; b < 16; ++b)
        #pragma unroll
        for (int c = 0; c < 4; ++c) acc[b][c] = 0.f;

    if (f) {
        const float* Wp = (const float*)W_fc + (size_t)(k0 + kr) * OD + ng * 4;
        #pragma unroll 4
        for (int kk = 0; kk < FC_KC; kk += 8) {
            f4v w4 = *(const f4v*)(Wp + (size_t)kk * OD);
            int kl = kk + kr;
            #pragma unroll
            for (int q = 0; q < 4; ++q) {
                f4v uq = *(const f4v*)&u_lds[kl][q * 4];
                #pragma unroll
                for (int c = 0; c < 4; ++c) acc[q * 4 + c] += uq[c] * w4;
            }
        }
    } else {
        const bf16* Wp = (const bf16*)W_fc + (size_t)(k0 + kr) * OD + ng * 4;
        #pragma unroll 4
        for (int kk = 0; kk < FC_KC; kk += 8) {
            bf4v wv = *(const bf4v*)(Wp + (size_t)kk * OD);
            f4v w4;
            #pragma unroll
            for (int c = 0; c < 4; ++c) w4[c] = (float)wv[c];
            int kl = kk + kr;
            #pragma unroll
            for (int q = 0; q < 4; ++q) {
                f4v uq = *(const f4v*)&u_lds[kl][q * 4];
                #pragma unroll
                for (int c = 0; c < 4; ++c) acc[q * 4 + c] += uq[c] * w4;
            }
        }
    }

    // reduce the 8 kr partials: shfl halves within wave, then LDS across 4 waves
    #pragma unroll
    for (int b = 0; b < 16; ++b)
        #pragma unroll
        for (int c = 0; c < 4; ++c) acc[b][c] += __shfl_down(acc[b][c], 32);
    __syncthreads();                               // u_lds reads done; reuse as reduce buf
    f4v* redv = (f4v*)&u_lds[0][0];                // 2048 f4v = 32 KB
    const int w = tid >> 6, lane = tid & 63;
    if (lane < 32) {
        #pragma unroll
        for (int b = 0; b < 16; ++b) redv[(b * 4 + w) * 32 + lane] = acc[b];
    }
    __syncthreads();
    #pragma unroll
    for (int i = 0; i < 2; ++i) {
        int og = tid + i * 256;                    // 0..511 = (b, ng)
        int b = og >> 5, ngo = og & 31;
        f4v s = {0.f, 0.f, 0.f, 0.f};
        #pragma unroll
        for (int w2 = 0; w2 < 4; ++w2) s += redv[(b * 4 + w2) * 32 + ngo];
        *(f4v*)&part[(size_t)blockIdx.x * (Bz * OD) + b * OD + ngo * 4] = s;
    }
}

__global__ __launch_bounds__(256) void fc_reduce_kernel(const float* __restrict__ part,
                                                        float* __restrict__ accb) {
    const int o = blockIdx.x * 256 + threadIdx.x;  // 0..2047
    const int s0 = blockIdx.y * (FC_BLOCKS / 16);  // 16 slices of 64 blocks
    float s = 0.f;
    for (int p = s0; p < s0 + FC_BLOCKS / 16; ++p) s += part[(size_t)p * (Bz * OD) + o];
    atomicAdd(&accb[o], s);
}

__global__ void fc_final_kernel(const float* __restrict__ accbuf,
                                const void* __restrict__ b_fc, void* __restrict__ out,
                                const int* __restrict__ flag) {
    const bool f = (*flag != 0);
    int i = blockIdx.x * 256 + threadIdx.x;
    if (i < Bz * OD) {
        float v = accbuf[i] + ldv(b_fc, i & (OD - 1), f);
        if (f) ((float*)out)[i] = v;
        else   ((bf16*)out)[i]  = __float2bfloat16(v);
    }
}

extern "C" void kernel_launch(void* const* d_in, const int* in_sizes, int n_in,
                              void* d_out, int out_size, void* d_ws, size_t ws_size,
                              hipStream_t stream) {
    const void* x       = d_in[0];
    const void* W_in    = d_in[1];
    const void* conv_w  = d_in[2];
    const void* conv_b  = d_in[3];
    const void* W_xproj = d_in[4];
    const void* W_dt    = d_in[5];
    const void* b_dt    = d_in[6];
    const void* A_log   = d_in[7];
    const void* Dp      = d_in[8];
    const void* W_out   = d_in[9];
    const void* W_fc    = d_in[10];
    const void* b_fc    = d_in[11];

    // workspace layout (bytes)
    char* ws = (char*)d_ws;
    bf16*     xin    = (bf16*)(ws);                      // [0,32M)
    float*    part   = (float*)(ws);                     // 8 MB (xin dead by K7)
    bf16*     yzs    = (bf16*)(ws + 33554432ull);        // [32M,64M) silu(z) -> y
    bf16*     xc     = (bf16*)(ws + 67108864ull);        // [64M,96M)
    float*    x_dbl  = (float*)(ws + 100663296ull);      // [96M,100M) fp32
    bf16*     xb     = (bf16*)(ws + 104857600ull);       // [100M,116M) canonical x; outp aliases
    bf16*     outp   = (bf16*)(ws + 104857600ull);
    float*    hbuf   = (float*)(ws + 167772160ull);      // 160M, 16 MB
    float*    dtsum  = (float*)(ws + 188743680ull);      // 180M, 1 MB
    bf16*     Wt_in  = (bf16*)(ws + 199229440ull);       // 190M, 2 MB  [2048][512]
    bf16*     Wt_out = (bf16*)(ws + 202375168ull);       // 193M, 1 MB  [512][1024]
    bf16*     Wt_xp  = (bf16*)(ws + 204472320ull);       // 195M, 128KB [64][1024]
    float*    accb   = (float*)(ws + 205520896ull);      // 196M, 8 KB
    int*      flag   = (int*)(ws + 206569472ull);        // 197M

    dim3 blk(256);
    hipMemsetAsync(flag, 0, 4, stream);
    detect_kernel<<<256, blk, 0, stream>>>(x, flag);
    // canonicalize / transpose to bf16 B^T (transposes fused into one dispatch)
    canon_kernel<<<(Mrows * DM) / 2048, blk, 0, stream>>>(x, xb, flag);
    transpose3_kernel<<<1600, blk, 0, stream>>>(W_in, W_out, W_xproj,
                                                Wt_in, Wt_out, Wt_xp, flag);
    // K1: [xin | silu(z)] = x @ W_in  (single fused GEMM, split epilogue)
    hipLaunchKernelGGL((gemm_bt<128, 128, true, false, 4, 1>),
                       dim3(2 * DI / 128, Mrows / 128), blk, 0, stream,
                       xb, DM, Wt_in, DM, xin, yzs, DI, DM);
    // K2: xc = silu(conv(xin))
    conv_silu_kernel<<<(Mrows * DI) / 256, blk, 0, stream>>>(xin, conv_w, conv_b, xc, flag);
    // K3: x_dbl = xc @ W_xproj (fp32 out, measured-good 128-row config)
    hipLaunchKernelGGL((gemm_bt<128, 64, false, true, 0, 1>),
                       dim3(1, Mrows / 128), blk, 0, stream,
                       xc, DI, Wt_xp, DI, x_dbl, (void*)0, XD, DI);
    // K5: chunked scan; dt fused in both passes; A-structure fast path (E^(s+1))
    scan_pass1<<<dim3(NC, DI / 256, Bz), blk, 0, stream>>>(x_dbl, xc, A_log, W_dt, b_dt,
                                                           hbuf, dtsum, flag);
    scan_prefix<<<(Bz * DI * ST) / 256, blk, 0, stream>>>(hbuf, dtsum, A_log, flag);
    scan_pass2<<<dim3(NC, DI / 256, Bz), blk, 0, stream>>>(x_dbl, xc, A_log, W_dt, b_dt,
                                                           Dp, yzs, hbuf, flag);
    // K6: outp = y @ W_out
    hipLaunchKernelGGL((gemm_bt<128, 128, false, false, 2, 1>),
                       dim3(DM / 128, Mrows / 128), blk, 0, stream,
                       yzs, DI, Wt_out, DI, outp, (void*)0, DM, DI);
    // K7: final FC (vectorized, LDS-staged, deterministic partials)
    hipMemsetAsync(accb, 0, Bz * OD * sizeof(float), stream);
    fc_partial_kernel<<<FC_BLOCKS, blk, 0, stream>>>(outp, W_fc, part, flag);
    fc_reduce_kernel<<<dim3((Bz * OD) / 256, 16), blk, 0, stream>>>(part, accb);
    fc_final_kernel<<<(Bz * OD + 255) / 256, blk, 0, stream>>>(accb, b_fc, d_out, flag);
}